// Round 1
// baseline (1237.936 us; speedup 1.0000x reference)
//
#include <hip/hip_runtime.h>
#include <math.h>
#include <float.h>

// Problem: desc1 (B,128) f32, desc2 (B,128) f32, B=16384.
// d2(i,j) = |a_i|^2 + |b_j|^2 - 2 a_i.b_j ; per-row two smallest (by sqrt(d2) == by d2),
// ratio = sqrt(d2_0)/sqrt(d2_1), mask = ratio <= 0.8.
// Out (flat f32): [0,B) match_dists ; [B,3B) matches_idxs as floats ; [3B,4B) mask 0/1.

#define BM   64   // rows per block
#define BN   64   // cols per tile
#define KS   32   // K slab staged in LDS
#define CS   8    // column splits
#define LDA  36   // padded LDS row stride (floats): +4 keeps b128 alignment, spreads banks

__global__ void norms_kernel(const float* __restrict__ d1,
                             const float* __restrict__ d2,
                             float* __restrict__ sq, int B) {
  int gid  = blockIdx.x * blockDim.x + threadIdx.x;
  int wid  = gid >> 6;
  int lane = gid & 63;
  if (wid >= 2 * B) return;
  const float* src = (wid < B) ? (d1 + (size_t)wid * 128)
                               : (d2 + (size_t)(wid - B) * 128);
  float2 v = ((const float2*)src)[lane];
  float s = fmaf(v.x, v.x, v.y * v.y);
  #pragma unroll
  for (int off = 32; off > 0; off >>= 1) s += __shfl_down(s, off, 64);
  if (lane == 0) sq[wid] = s;
}

// 1 wave per block. Each block: 64 rows x 2048 cols (1/8 of the column space).
// Micro-tile 8x8 per thread; rows of thread = i0 + ig + 8r, cols = jb + jg + 8c.
__global__ __launch_bounds__(64, 2)
void nn_main(const float* __restrict__ d1, const float* __restrict__ d2,
             const float* __restrict__ sqb,
             float* __restrict__ p_d0, float* __restrict__ p_d1,
             int* __restrict__ p_j0, int B) {
  __shared__ float a_s[BM][LDA];
  __shared__ float b_s[BN][LDA];

  const int lane = threadIdx.x;
  const int ig = lane >> 3;      // 0..7 row group
  const int jg = lane & 7;       // 0..7 col group
  const int rb    = blockIdx.x >> 3;
  const int cspl  = blockIdx.x & 7;
  const int i0    = rb * BM;
  const int colsPer = B / CS;              // 2048
  const int cbase = cspl * colsPer;
  const int ntiles = colsPer / BN;         // 32

  float best0[8], best1[8];
  int   bj[8];
  #pragma unroll
  for (int r = 0; r < 8; ++r) { best0[r] = FLT_MAX; best1[r] = FLT_MAX; bj[r] = 0x7fffffff; }

  for (int ct = 0; ct < ntiles; ++ct) {
    const int jb = cbase + ct * BN;
    float acc[8][8];
    #pragma unroll
    for (int r = 0; r < 8; ++r)
      #pragma unroll
      for (int c = 0; c < 8; ++c) acc[r][c] = 0.f;

    for (int ks = 0; ks < 128; ks += KS) {
      __syncthreads();   // previous slab fully consumed
      // stage A slab + B slab: 64 rows x 32 k each = 512 float4 each, 8 per thread
      #pragma unroll
      for (int e = 0; e < 8; ++e) {
        int f4  = lane + e * 64;     // 0..511
        int row = f4 >> 3;           // 8 float4 per row
        int k4  = f4 & 7;
        float4 va = *(const float4*)(d1 + (size_t)(i0 + row) * 128 + ks + k4 * 4);
        *(float4*)&a_s[row][k4 * 4] = va;
        float4 vb = *(const float4*)(d2 + (size_t)(jb + row) * 128 + ks + k4 * 4);
        *(float4*)&b_s[row][k4 * 4] = vb;
      }
      __syncthreads();

      #pragma unroll
      for (int kk = 0; kk < KS; kk += 4) {
        float4 a[8], b[8];
        #pragma unroll
        for (int r = 0; r < 8; ++r) a[r] = *(const float4*)&a_s[ig + 8 * r][kk];
        #pragma unroll
        for (int c = 0; c < 8; ++c) b[c] = *(const float4*)&b_s[jg + 8 * c][kk];
        #pragma unroll
        for (int r = 0; r < 8; ++r)
          #pragma unroll
          for (int c = 0; c < 8; ++c) {
            acc[r][c] = fmaf(a[r].x, b[c].x, acc[r][c]);
            acc[r][c] = fmaf(a[r].y, b[c].y, acc[r][c]);
            acc[r][c] = fmaf(a[r].z, b[c].z, acc[r][c]);
            acc[r][c] = fmaf(a[r].w, b[c].w, acc[r][c]);
          }
      }
    }

    // top-2 update; j ascending in c per thread => strict < keeps lowest index
    #pragma unroll
    for (int c = 0; c < 8; ++c) {
      int j = jb + jg + 8 * c;
      float sj = sqb[j];
      #pragma unroll
      for (int r = 0; r < 8; ++r) {
        float t = fmaf(-2.f, acc[r][c], sj);   // sqb[j] - 2*dot  (sqa added later)
        if (t < best0[r]) { best1[r] = best0[r]; best0[r] = t; bj[r] = j; }
        else if (t < best1[r]) { best1[r] = t; }
      }
    }
  }

  // butterfly merge across jg lanes (stride 1,2,4) with index tie-break
  #pragma unroll
  for (int off = 1; off < 8; off <<= 1) {
    #pragma unroll
    for (int r = 0; r < 8; ++r) {
      float e0 = __shfl_xor(best0[r], off, 64);
      float e1 = __shfl_xor(best1[r], off, 64);
      int   f0 = __shfl_xor(bj[r],    off, 64);
      if (e0 < best0[r] || (e0 == best0[r] && f0 < bj[r])) {
        best1[r] = fminf(best0[r], e1);
        best0[r] = e0;
        bj[r]    = f0;
      } else {
        best1[r] = fminf(best1[r], e0);
      }
    }
  }

  if (jg == 0) {
    #pragma unroll
    for (int r = 0; r < 8; ++r) {
      int row = i0 + ig + 8 * r;
      p_d0[row * CS + cspl] = best0[r];
      p_d1[row * CS + cspl] = best1[r];
      p_j0[row * CS + cspl] = bj[r];
    }
  }
}

__global__ void nn_final(const float* __restrict__ sqa,
                         const float* __restrict__ p_d0,
                         const float* __restrict__ p_d1,
                         const int* __restrict__ p_j0,
                         float* __restrict__ out, int B) {
  int row = blockIdx.x * blockDim.x + threadIdx.x;
  if (row >= B) return;
  float d0 = FLT_MAX, d1 = FLT_MAX;
  int j0 = 0x7fffffff;
  // cs ascending => ascending j ranges => sequential merge keeps lowest index on ties
  for (int cs = 0; cs < CS; ++cs) {
    float e0 = p_d0[row * CS + cs];
    float e1 = p_d1[row * CS + cs];
    int   f0 = p_j0[row * CS + cs];
    if (e0 < d0 || (e0 == d0 && f0 < j0)) {
      d1 = fminf(d0, e1);
      d0 = e0;
      j0 = f0;
    } else {
      d1 = fminf(d1, e0);
    }
  }
  float sa = sqa[row];
  float v0 = sqrtf(fmaxf(sa + d0, 0.f));
  float v1 = sqrtf(fmaxf(sa + d1, 0.f));
  float ratio = v0 / v1;
  bool m = (ratio <= 0.8f);
  out[row]             = m ? ratio : 0.f;
  out[B + row * 2]     = (float)row;
  out[B + row * 2 + 1] = (float)j0;
  out[3 * B + row]     = m ? 1.f : 0.f;
}

extern "C" void kernel_launch(void* const* d_in, const int* in_sizes, int n_in,
                              void* d_out, int out_size, void* d_ws, size_t ws_size,
                              hipStream_t stream) {
  const float* d1 = (const float*)d_in[0];
  const float* d2 = (const float*)d_in[1];
  const int B = in_sizes[0] / 128;   // 16384

  float* ws   = (float*)d_ws;
  float* sqa  = ws;                  // [0, B)
  float* sqb  = ws + B;              // [B, 2B)   (norms_kernel writes both as one array)
  float* p_d0 = ws + 2 * B;          // [2B, 10B)
  float* p_d1 = ws + 10 * B;         // [10B, 18B)
  int*   p_j0 = (int*)(ws + 18 * B); // [18B, 26B)
  float* out  = (float*)d_out;

  // norms: one wave per row, 2B rows
  int nthreads = 2 * B * 64;
  norms_kernel<<<(nthreads + 255) / 256, 256, 0, stream>>>(d1, d2, sqa, B);

  // main: (B/BM) row blocks x CS column splits, 64 threads each
  nn_main<<<(B / BM) * CS, 64, 0, stream>>>(d1, d2, sqb, p_d0, p_d1, p_j0, B);

  // final merge + outputs
  nn_final<<<(B + 255) / 256, 256, 0, stream>>>(sqa, p_d0, p_d1, p_j0, out, B);
}

// Round 3
// 745.207 us; speedup vs baseline: 1.6612x; 1.6612x over previous
//
#include <hip/hip_runtime.h>
#include <math.h>
#include <float.h>

// NearestNeighborRatio: desc1/desc2 (B=16384, D=128) f32.
// d2(i,j) = |a_i|^2 + |b_j|^2 - 2 a_i.b_j; per-row top-2, ratio = sqrt(d0/d1), mask = ratio<=0.8.
// Strategy: f16 hi/lo split (x = hi + lo), dot via 3 MFMAs (hi*hi + hi*lo + lo*hi) in fp32 acc.
// Out (flat f32): [0,B) match_dists ; [B,3B) matches_idxs as floats ; [3B,4B) mask 0/1.

typedef __attribute__((ext_vector_type(4))) float     f32x4;
typedef __attribute__((ext_vector_type(8))) _Float16  half8;
typedef __attribute__((ext_vector_type(4))) _Float16  half4;

#define D_     128
#define BM_    128   // rows per block
#define BN_    128   // cols per iter
#define CS_    4     // column splits
#define PARTS_ 8     // partials per row = CS_ * 2 (wc halves)

__global__ void norms_kernel(const float* __restrict__ d1,
                             const float* __restrict__ d2,
                             float* __restrict__ sq, int B) {
  int gid  = blockIdx.x * blockDim.x + threadIdx.x;
  int wid  = gid >> 6;
  int lane = gid & 63;
  if (wid >= 2 * B) return;
  const float* src = (wid < B) ? (d1 + (size_t)wid * D_)
                               : (d2 + (size_t)(wid - B) * D_);
  float2 v = ((const float2*)src)[lane];
  float s = fmaf(v.x, v.x, v.y * v.y);
  #pragma unroll
  for (int off = 32; off > 0; off >>= 1) s += __shfl_down(s, off, 64);
  if (lane == 0) sq[wid] = s;
}

// f32 -> (hi, lo) f16 planes, float4-vectorized
__global__ void convert_kernel(const float* __restrict__ d1, const float* __restrict__ d2,
                               _Float16* __restrict__ Ahi, _Float16* __restrict__ Alo,
                               _Float16* __restrict__ Bhi, _Float16* __restrict__ Blo,
                               int n4) {
  int i = blockIdx.x * blockDim.x + threadIdx.x;
  const float* src; _Float16 *dh, *dl; int j;
  if (i < n4)           { src = d1; dh = Ahi; dl = Alo; j = i; }
  else if (i < 2 * n4)  { src = d2; dh = Bhi; dl = Blo; j = i - n4; }
  else return;
  float4 v = ((const float4*)src)[j];
  half4 hv, lv;
  hv.x = (_Float16)v.x; lv.x = (_Float16)(v.x - (float)hv.x);
  hv.y = (_Float16)v.y; lv.y = (_Float16)(v.y - (float)hv.y);
  hv.z = (_Float16)v.z; lv.z = (_Float16)(v.z - (float)hv.z);
  hv.w = (_Float16)v.w; lv.w = (_Float16)(v.w - (float)hv.w);
  ((half4*)dh)[j] = hv;
  ((half4*)dl)[j] = lv;
}

// LDS map (dynamic, 128 KiB):
//   [0,32K)    A_hi  [128 rows][128 f16], row stride 256B, byte ^= (row&7)<<4
//   [32K,64K)  A_lo
//   [64K,96K)  B_hi  [128 cols][128 f16], same swizzle
//   [96K,128K) B_lo
__global__ __launch_bounds__(256, 1)
void nn_mfma(const _Float16* __restrict__ Ahi, const _Float16* __restrict__ Alo,
             const _Float16* __restrict__ Bhi, const _Float16* __restrict__ Blo,
             const float* __restrict__ sqb,
             float* __restrict__ p_d0, float* __restrict__ p_d1,
             int* __restrict__ p_j0, int B) {
  extern __shared__ char smem[];
  const int tid  = threadIdx.x;
  const int lane = tid & 63;
  const int wid  = tid >> 6;
  const int wr   = wid >> 1;       // row half (0,1)
  const int wc   = wid & 1;        // col half (0,1)
  const int l15  = lane & 15;
  const int g    = lane >> 4;      // k-group / row-subgroup

  const int nrb  = B / BM_;
  const int rb   = blockIdx.x % nrb;
  const int cspl = blockIdx.x / nrb;
  const int i0   = rb * BM_;
  const int strip = B / CS_;
  const int c0   = cspl * strip;
  const int niter = strip / BN_;

  // ---- stage A (full K, hi+lo), once.  16-byte chunks: 2 planes*128 rows*16 chunks = 4096 ----
  #pragma unroll
  for (int e = 0; e < 16; ++e) {
    int c     = tid + e * 256;        // 0..4095
    int plane = c >> 11;              // 0 hi, 1 lo
    int row   = (c >> 4) & 127;
    int ks    = c & 15;               // 16B chunk within row
    int4 v = *(const int4*)((plane ? Alo : Ahi) + (size_t)(i0 + row) * D_ + ks * 8);
    *(int4*)(smem + plane * 32768 + row * 256 + ((ks * 16) ^ ((row & 7) << 4))) = v;
  }

  float best0[16], best1[16]; int bj[16];
  #pragma unroll
  for (int s = 0; s < 16; ++s) { best0[s] = FLT_MAX; best1[s] = FLT_MAX; bj[s] = 0x7fffffff; }

  for (int it = 0; it < niter; ++it) {
    const int jb = c0 + it * BN_;
    // ---- stage B tile (full K, hi+lo) ----
    #pragma unroll
    for (int e = 0; e < 16; ++e) {
      int c     = tid + e * 256;
      int plane = c >> 11;
      int col   = (c >> 4) & 127;
      int ks    = c & 15;
      int4 v = *(const int4*)((plane ? Blo : Bhi) + (size_t)(jb + col) * D_ + ks * 8);
      *(int4*)(smem + 65536 + plane * 32768 + col * 256 + ((ks * 16) ^ ((col & 7) << 4))) = v;
    }
    __syncthreads();   // A (first iter) + B visible

    f32x4 acc[4][4];
    #pragma unroll
    for (int mf = 0; mf < 4; ++mf)
      #pragma unroll
      for (int nf = 0; nf < 4; ++nf) acc[mf][nf] = (f32x4){0.f, 0.f, 0.f, 0.f};

    #pragma unroll
    for (int kk = 0; kk < 4; ++kk) {
      const int kbyte = kk * 64 + g * 16;   // this lane's 8 f16 within the row
      half8 ah[4], al[4], bh[4], bl[4];
      #pragma unroll
      for (int mf = 0; mf < 4; ++mf) {
        int row = wr * 64 + mf * 16 + l15;
        int off = row * 256 + (kbyte ^ ((row & 7) << 4));
        ah[mf] = *(const half8*)(smem + off);
        al[mf] = *(const half8*)(smem + 32768 + off);
      }
      #pragma unroll
      for (int nf = 0; nf < 4; ++nf) {
        int col = wc * 64 + nf * 16 + l15;
        int off = col * 256 + (kbyte ^ ((col & 7) << 4));
        bh[nf] = *(const half8*)(smem + 65536 + off);
        bl[nf] = *(const half8*)(smem + 98304 + off);
      }
      #pragma unroll
      for (int mf = 0; mf < 4; ++mf)
        #pragma unroll
        for (int nf = 0; nf < 4; ++nf) {
          acc[mf][nf] = __builtin_amdgcn_mfma_f32_16x16x32_f16(ah[mf], bh[nf], acc[mf][nf], 0, 0, 0);
          acc[mf][nf] = __builtin_amdgcn_mfma_f32_16x16x32_f16(ah[mf], bl[nf], acc[mf][nf], 0, 0, 0);
          acc[mf][nf] = __builtin_amdgcn_mfma_f32_16x16x32_f16(al[mf], bh[nf], acc[mf][nf], 0, 0, 0);
        }
    }
    __syncthreads();   // all frag reads retired; next iter may overwrite B

    // ---- top-2 fold (registers only) ----
    // C/D layout: col = lane&15, row = (lane>>4)*4 + reg  (16x16 frag)
    #pragma unroll
    for (int nf = 0; nf < 4; ++nf) {
      int colg = jb + wc * 64 + nf * 16 + l15;
      float sj = sqb[colg];
      #pragma unroll
      for (int mf = 0; mf < 4; ++mf)
        #pragma unroll
        for (int r = 0; r < 4; ++r) {
          float t = fmaf(-2.f, acc[mf][nf][r], sj);
          int s = mf * 4 + r;
          if (t < best0[s])      { best1[s] = best0[s]; best0[s] = t; bj[s] = colg; }
          else if (t < best1[s]) { best1[s] = t; }
        }
    }
  }

  // ---- merge across the 16 col-lanes (same g group), index tie-break ----
  #pragma unroll
  for (int off = 1; off < 16; off <<= 1) {
    #pragma unroll
    for (int s = 0; s < 16; ++s) {
      float e0 = __shfl_xor(best0[s], off, 64);
      float e1 = __shfl_xor(best1[s], off, 64);
      int   f0 = __shfl_xor(bj[s],    off, 64);
      if (e0 < best0[s] || (e0 == best0[s] && f0 < bj[s])) {
        best1[s] = fminf(best0[s], e1);
        best0[s] = e0;
        bj[s]    = f0;
      } else {
        best1[s] = fminf(best1[s], e0);
      }
    }
  }

  if (l15 == 0) {
    int part = cspl * 2 + wc;
    #pragma unroll
    for (int s = 0; s < 16; ++s) {
      int mf = s >> 2, r = s & 3;
      int row = i0 + wr * 64 + mf * 16 + g * 4 + r;
      p_d0[row * PARTS_ + part] = best0[s];
      p_d1[row * PARTS_ + part] = best1[s];
      p_j0[row * PARTS_ + part] = bj[s];
    }
  }
}

__global__ void nn_final(const float* __restrict__ sqa,
                         const float* __restrict__ p_d0,
                         const float* __restrict__ p_d1,
                         const int* __restrict__ p_j0,
                         float* __restrict__ out, int B) {
  int row = blockIdx.x * blockDim.x + threadIdx.x;
  if (row >= B) return;
  float d0 = FLT_MAX, d1 = FLT_MAX;
  int j0 = 0x7fffffff;
  for (int cs = 0; cs < PARTS_; ++cs) {
    float e0 = p_d0[row * PARTS_ + cs];
    float e1 = p_d1[row * PARTS_ + cs];
    int   f0 = p_j0[row * PARTS_ + cs];
    if (e0 < d0 || (e0 == d0 && f0 < j0)) {
      d1 = fminf(d0, e1);
      d0 = e0;
      j0 = f0;
    } else {
      d1 = fminf(d1, e0);
    }
  }
  float sa = sqa[row];
  float v0 = sqrtf(fmaxf(sa + d0, 0.f));
  float v1 = sqrtf(fmaxf(sa + d1, 0.f));
  float ratio = v0 / v1;
  bool m = (ratio <= 0.8f);
  out[row]             = m ? ratio : 0.f;
  out[B + row * 2]     = (float)row;
  out[B + row * 2 + 1] = (float)j0;
  out[3 * B + row]     = m ? 1.f : 0.f;
}

extern "C" void kernel_launch(void* const* d_in, const int* in_sizes, int n_in,
                              void* d_out, int out_size, void* d_ws, size_t ws_size,
                              hipStream_t stream) {
  const float* d1 = (const float*)d_in[0];
  const float* d2 = (const float*)d_in[1];
  const int B = in_sizes[0] / D_;    // 16384

  float* ws   = (float*)d_ws;
  float* sqa  = ws;                       // [0, B)
  float* sqb  = ws + B;                   // [B, 2B)
  float* p_d0 = ws + 2 * B;               // [2B, 10B)
  float* p_d1 = ws + 10 * B;              // [10B, 18B)
  int*   p_j0 = (int*)(ws + 18 * B);      // [18B, 26B)
  _Float16* Ahi = (_Float16*)(ws + 26 * B);
  _Float16* Alo = Ahi + (size_t)B * D_;
  _Float16* Bhi = Alo + (size_t)B * D_;
  _Float16* Blo = Bhi + (size_t)B * D_;

  // norms
  int nthreads = 2 * B * 64;
  norms_kernel<<<(nthreads + 255) / 256, 256, 0, stream>>>(d1, d2, sqa, B);

  // f32 -> f16 hi/lo planes
  int n4 = B * D_ / 4;
  convert_kernel<<<(2 * n4 + 255) / 256, 256, 0, stream>>>(d1, d2, Ahi, Alo, Bhi, Blo, n4);

  // main MFMA kernel: 128 KiB dynamic LDS
  hipFuncSetAttribute((const void*)nn_mfma,
                      hipFuncAttributeMaxDynamicSharedMemorySize, 131072);
  nn_mfma<<<(B / BM_) * CS_, 256, 131072, stream>>>(Ahi, Alo, Bhi, Blo, sqb,
                                                    p_d0, p_d1, p_j0, B);

  // final merge + outputs
  nn_final<<<(B + 255) / 256, 256, 0, stream>>>(sqa, p_d0, p_d1, p_j0, (float*)d_out, B);
}

// Round 4
// 309.648 us; speedup vs baseline: 3.9979x; 2.4066x over previous
//
#include <hip/hip_runtime.h>
#include <math.h>
#include <float.h>

// NearestNeighborRatio: desc1/desc2 (B=16384, D=128) f32.
// d2(i,j) = |a_i|^2 + |b_j|^2 - 2 a_i.b_j; per-row top-2, ratio = sqrt(d0/d1), mask = ratio<=0.8.
// f16 hi/lo split (x = hi + lo): dot via 3 MFMAs (hh + hl + lh) in fp32 acc.
// v3: A fragments in registers (loaded once), LDS holds only B (64KB) -> 2 blocks/CU.
// Out (flat f32): [0,B) match_dists ; [B,3B) matches_idxs as floats ; [3B,4B) mask 0/1.

typedef __attribute__((ext_vector_type(4))) float     f32x4;
typedef __attribute__((ext_vector_type(8))) _Float16  half8;
typedef __attribute__((ext_vector_type(4))) _Float16  half4;

#define D_     128
#define BM_    64    // rows per block
#define BN_    128   // cols per iter
#define CS_    2     // column splits
#define PARTS_ 4     // partials per row = CS_ * 2 (wc halves)

__global__ void norms_kernel(const float* __restrict__ d1,
                             const float* __restrict__ d2,
                             float* __restrict__ sq, int B) {
  int gid  = blockIdx.x * blockDim.x + threadIdx.x;
  int wid  = gid >> 6;
  int lane = gid & 63;
  if (wid >= 2 * B) return;
  const float* src = (wid < B) ? (d1 + (size_t)wid * D_)
                               : (d2 + (size_t)(wid - B) * D_);
  float2 v = ((const float2*)src)[lane];
  float s = fmaf(v.x, v.x, v.y * v.y);
  #pragma unroll
  for (int off = 32; off > 0; off >>= 1) s += __shfl_down(s, off, 64);
  if (lane == 0) sq[wid] = s;
}

__global__ void convert_kernel(const float* __restrict__ d1, const float* __restrict__ d2,
                               _Float16* __restrict__ Ahi, _Float16* __restrict__ Alo,
                               _Float16* __restrict__ Bhi, _Float16* __restrict__ Blo,
                               int n4) {
  int i = blockIdx.x * blockDim.x + threadIdx.x;
  const float* src; _Float16 *dh, *dl; int j;
  if (i < n4)           { src = d1; dh = Ahi; dl = Alo; j = i; }
  else if (i < 2 * n4)  { src = d2; dh = Bhi; dl = Blo; j = i - n4; }
  else return;
  float4 v = ((const float4*)src)[j];
  half4 hv, lv;
  hv.x = (_Float16)v.x; lv.x = (_Float16)(v.x - (float)hv.x);
  hv.y = (_Float16)v.y; lv.y = (_Float16)(v.y - (float)hv.y);
  hv.z = (_Float16)v.z; lv.z = (_Float16)(v.z - (float)hv.z);
  hv.w = (_Float16)v.w; lv.w = (_Float16)(v.w - (float)hv.w);
  ((half4*)dh)[j] = hv;
  ((half4*)dl)[j] = lv;
}

// LDS (dynamic 64KB): B tile only.
//   [0,32K)    B_hi  [128 cols][128 f16], row stride 256B, byte ^= (col&7)<<4
//   [32K,64K)  B_lo
__global__ __launch_bounds__(256, 2)
void nn_mfma(const _Float16* __restrict__ Ahi, const _Float16* __restrict__ Alo,
             const _Float16* __restrict__ Bhi, const _Float16* __restrict__ Blo,
             const float* __restrict__ sqb,
             float* __restrict__ p_d0, float* __restrict__ p_d1,
             int* __restrict__ p_j0, int B) {
  extern __shared__ char smem[];
  const int tid  = threadIdx.x;
  const int lane = tid & 63;
  const int wid  = tid >> 6;
  const int wr   = wid >> 1;       // row half (0,1): rows wr*32..wr*32+31
  const int wc   = wid & 1;        // col half (0,1): cols wc*64..wc*64+63
  const int l15  = lane & 15;
  const int g    = lane >> 4;

  const int nrb  = B / BM_;            // 256
  const int rb   = blockIdx.x % nrb;
  const int cspl = blockIdx.x / nrb;
  const int i0   = rb * BM_;
  const int strip = B / CS_;           // 8192
  const int c0   = cspl * strip;
  const int niter = strip / BN_;       // 64

  // ---- A fragments -> registers, once (fragment-layout gather from global) ----
  half8 ah[2][4], al[2][4];
  #pragma unroll
  for (int mf = 0; mf < 2; ++mf) {
    int row = i0 + wr * 32 + mf * 16 + l15;
    const _Float16* pa = Ahi + (size_t)row * D_ + g * 8;
    const _Float16* pl = Alo + (size_t)row * D_ + g * 8;
    #pragma unroll
    for (int kk = 0; kk < 4; ++kk) {
      ah[mf][kk] = *(const half8*)(pa + kk * 32);
      al[mf][kk] = *(const half8*)(pl + kk * 32);
    }
  }

  // ---- staging geometry: thread writes 16B chunks; col advances by 16 per e ----
  const int scol  = tid >> 4;                  // 0..15
  const int sks   = tid & 15;                  // 16B chunk within a col's 256B row
  const int wbase = scol * 256 + ((sks * 16) ^ ((scol & 7) << 4));
  const _Float16* pH = Bhi + (size_t)(c0 + scol) * D_ + sks * 8;
  const _Float16* pL = Blo + (size_t)(c0 + scol) * D_ + sks * 8;

  // ---- fragment-read bases per kk (hi plane; +32768 for lo; +nf*4096 immediates) ----
  int rbk[4];
  #pragma unroll
  for (int kk = 0; kk < 4; ++kk)
    rbk[kk] = (wc * 64 + l15) * 256 + ((kk * 64 + g * 16) ^ ((l15 & 7) << 4));

  const int colbase = c0 + wc * 64 + l15;

  float best0[8], best1[8]; int bj[8];
  #pragma unroll
  for (int s = 0; s < 8; ++s) { best0[s] = FLT_MAX; best1[s] = FLT_MAX; bj[s] = 0x7fffffff; }

  for (int it = 0; it < niter; ++it) {
    __syncthreads();   // all waves done reading previous B tile
    #pragma unroll
    for (int e = 0; e < 8; ++e) {
      int4 v = *(const int4*)(pH + e * 2048);
      *(int4*)(smem + wbase + e * 4096) = v;
    }
    #pragma unroll
    for (int e = 0; e < 8; ++e) {
      int4 v = *(const int4*)(pL + e * 2048);
      *(int4*)(smem + 32768 + wbase + e * 4096) = v;
    }
    pH += BN_ * D_;
    pL += BN_ * D_;
    __syncthreads();   // B tile visible

    f32x4 acc[2][4];
    #pragma unroll
    for (int mf = 0; mf < 2; ++mf)
      #pragma unroll
      for (int nf = 0; nf < 4; ++nf) acc[mf][nf] = (f32x4){0.f, 0.f, 0.f, 0.f};

    #pragma unroll
    for (int kk = 0; kk < 4; ++kk) {
      half8 bh[4], bl[4];
      #pragma unroll
      for (int nf = 0; nf < 4; ++nf) {
        bh[nf] = *(const half8*)(smem + rbk[kk] + nf * 4096);
        bl[nf] = *(const half8*)(smem + rbk[kk] + nf * 4096 + 32768);
      }
      #pragma unroll
      for (int mf = 0; mf < 2; ++mf)
        #pragma unroll
        for (int nf = 0; nf < 4; ++nf) {
          acc[mf][nf] = __builtin_amdgcn_mfma_f32_16x16x32_f16(ah[mf][kk], bh[nf], acc[mf][nf], 0, 0, 0);
          acc[mf][nf] = __builtin_amdgcn_mfma_f32_16x16x32_f16(ah[mf][kk], bl[nf], acc[mf][nf], 0, 0, 0);
          acc[mf][nf] = __builtin_amdgcn_mfma_f32_16x16x32_f16(al[mf][kk], bh[nf], acc[mf][nf], 0, 0, 0);
        }
    }

    // ---- branchless top-2 fold. C/D layout: col = lane&15, row = (lane>>4)*4 + reg ----
    #pragma unroll
    for (int nf = 0; nf < 4; ++nf) {
      int colg = colbase + it * BN_ + nf * 16;
      float sj = sqb[colg];
      #pragma unroll
      for (int mf = 0; mf < 2; ++mf)
        #pragma unroll
        for (int r = 0; r < 4; ++r) {
          int s = mf * 4 + r;
          float t = fmaf(-2.f, acc[mf][nf][r], sj);
          bool lt0 = t < best0[s];
          best1[s] = fminf(best1[s], fmaxf(t, best0[s]));
          best0[s] = fminf(t, best0[s]);
          bj[s]    = lt0 ? colg : bj[s];
        }
    }
  }

  // ---- merge across the 16 col-lanes (same g), index tie-break ----
  #pragma unroll
  for (int off = 1; off < 16; off <<= 1) {
    #pragma unroll
    for (int s = 0; s < 8; ++s) {
      float e0 = __shfl_xor(best0[s], off, 64);
      float e1 = __shfl_xor(best1[s], off, 64);
      int   f0 = __shfl_xor(bj[s],    off, 64);
      if (e0 < best0[s] || (e0 == best0[s] && f0 < bj[s])) {
        best1[s] = fminf(best0[s], e1);
        best0[s] = e0;
        bj[s]    = f0;
      } else {
        best1[s] = fminf(best1[s], e0);
      }
    }
  }

  if (l15 == 0) {
    int part = cspl * 2 + wc;
    #pragma unroll
    for (int s = 0; s < 8; ++s) {
      int mf = s >> 2, r = s & 3;
      int row = i0 + wr * 32 + mf * 16 + g * 4 + r;
      p_d0[row * PARTS_ + part] = best0[s];
      p_d1[row * PARTS_ + part] = best1[s];
      p_j0[row * PARTS_ + part] = bj[s];
    }
  }
}

__global__ void nn_final(const float* __restrict__ sqa,
                         const float* __restrict__ p_d0,
                         const float* __restrict__ p_d1,
                         const int* __restrict__ p_j0,
                         float* __restrict__ out, int B) {
  int row = blockIdx.x * blockDim.x + threadIdx.x;
  if (row >= B) return;
  float d0 = FLT_MAX, d1 = FLT_MAX;
  int j0 = 0x7fffffff;
  for (int cs = 0; cs < PARTS_; ++cs) {
    float e0 = p_d0[row * PARTS_ + cs];
    float e1 = p_d1[row * PARTS_ + cs];
    int   f0 = p_j0[row * PARTS_ + cs];
    if (e0 < d0 || (e0 == d0 && f0 < j0)) {
      d1 = fminf(d0, e1);
      d0 = e0;
      j0 = f0;
    } else {
      d1 = fminf(d1, e0);
    }
  }
  float sa = sqa[row];
  float v0 = sqrtf(fmaxf(sa + d0, 0.f));
  float v1 = sqrtf(fmaxf(sa + d1, 0.f));
  float ratio = v0 / v1;
  bool m = (ratio <= 0.8f);
  out[row]             = m ? ratio : 0.f;
  out[B + row * 2]     = (float)row;
  out[B + row * 2 + 1] = (float)j0;
  out[3 * B + row]     = m ? 1.f : 0.f;
}

extern "C" void kernel_launch(void* const* d_in, const int* in_sizes, int n_in,
                              void* d_out, int out_size, void* d_ws, size_t ws_size,
                              hipStream_t stream) {
  const float* d1 = (const float*)d_in[0];
  const float* d2 = (const float*)d_in[1];
  const int B = in_sizes[0] / D_;    // 16384

  float* ws   = (float*)d_ws;
  float* sqa  = ws;                       // [0, B)
  float* sqb  = ws + B;                   // [B, 2B)
  float* p_d0 = ws + 2 * B;               // [2B, 6B)
  float* p_d1 = ws + 6 * B;               // [6B, 10B)
  int*   p_j0 = (int*)(ws + 10 * B);      // [10B, 14B)
  _Float16* Ahi = (_Float16*)(ws + 14 * B);
  _Float16* Alo = Ahi + (size_t)B * D_;
  _Float16* Bhi = Alo + (size_t)B * D_;
  _Float16* Blo = Bhi + (size_t)B * D_;

  // norms
  int nthreads = 2 * B * 64;
  norms_kernel<<<(nthreads + 255) / 256, 256, 0, stream>>>(d1, d2, sqa, B);

  // f32 -> f16 hi/lo planes
  int n4 = B * D_ / 4;
  convert_kernel<<<(2 * n4 + 255) / 256, 256, 0, stream>>>(d1, d2, Ahi, Alo, Bhi, Blo, n4);

  // main MFMA kernel: 64 KiB dynamic LDS, 2 blocks/CU
  hipFuncSetAttribute((const void*)nn_mfma,
                      hipFuncAttributeMaxDynamicSharedMemorySize, 65536);
  nn_mfma<<<(B / BM_) * CS_, 256, 65536, stream>>>(Ahi, Alo, Bhi, Blo, sqb,
                                                   p_d0, p_d1, p_j0, B);

  // final merge + outputs
  nn_final<<<(B + 255) / 256, 256, 0, stream>>>(sqa, p_d0, p_d1, p_j0, (float*)d_out, B);
}

// Round 5
// 208.912 us; speedup vs baseline: 5.9256x; 1.4822x over previous
//
#include <hip/hip_runtime.h>
#include <math.h>
#include <float.h>
#include <stdint.h>

// NearestNeighborRatio: desc1/desc2 (B=16384, D=128) f32.
// d2(i,j) = |a_i|^2 + |b_j|^2 - 2 a_i.b_j; per-row top-2, ratio = sqrt(d0/d1), mask = ratio<=0.8.
// f16 hi/lo split (x = hi + lo): dot via 3 MFMAs (hh + hl + lh) in fp32 acc.
// v4: B pre-packed in MFMA fragment order in global; staged via global_load_lds (16B);
//     LDS reads are linear lane*16 + immediates -> zero bank conflicts.
// Out (flat f32): [0,B) match_dists ; [B,3B) matches_idxs as floats ; [3B,4B) mask 0/1.

typedef __attribute__((ext_vector_type(4))) float     f32x4;
typedef __attribute__((ext_vector_type(8))) _Float16  half8;

#define D_     128
#define BM_    64    // rows per block
#define BN_    128   // cols per iter (= one packed tile)
#define CS_    2     // column splits
#define PARTS_ 4     // partials per row = CS_ * 2 (wc halves)

__device__ __forceinline__ void gload_lds16(const void* g, void* l) {
  auto gp = (const __attribute__((address_space(1))) unsigned int*)(uintptr_t)g;
  auto lp = (__attribute__((address_space(3))) unsigned int*)(uintptr_t)l;
  __builtin_amdgcn_global_load_lds(gp, lp, 16, 0, 0);
}

__global__ void norms_kernel(const float* __restrict__ d1,
                             const float* __restrict__ d2,
                             float* __restrict__ sq, int B) {
  int gid  = blockIdx.x * blockDim.x + threadIdx.x;
  int wid  = gid >> 6;
  int lane = gid & 63;
  if (wid >= 2 * B) return;
  const float* src = (wid < B) ? (d1 + (size_t)wid * D_)
                               : (d2 + (size_t)(wid - B) * D_);
  float2 v = ((const float2*)src)[lane];
  float s = fmaf(v.x, v.x, v.y * v.y);
  #pragma unroll
  for (int off = 32; off > 0; off >>= 1) s += __shfl_down(s, off, 64);
  if (lane == 0) sq[wid] = s;
}

// A planes: row-major [B][128] f16.  B planes: packed fragment order:
//   f16 offset = tile*16384 + kk*4096 + nf*512 + g*128 + c15*8
//   holding desc2[tile*128 + nf*16 + c15][kk*32 + g*8 .. +8]
__global__ void convert_kernel(const float* __restrict__ d1, const float* __restrict__ d2,
                               _Float16* __restrict__ Ahi, _Float16* __restrict__ Alo,
                               _Float16* __restrict__ BhiP, _Float16* __restrict__ BloP,
                               int B) {
  int i = blockIdx.x * blockDim.x + threadIdx.x;
  int total = B * 16;                       // 8-elem groups per matrix
  if (i >= 2 * total) return;
  bool isB = i >= total;
  int j    = isB ? i - total : i;
  int desc = j >> 4;
  int seg  = j & 15;                        // 8-f32 group within the row
  const float* src = (isB ? d2 : d1) + (size_t)desc * D_ + seg * 8;
  float4 v0 = *(const float4*)(src);
  float4 v1 = *(const float4*)(src + 4);
  half8 hv, lv;
  float e[8] = {v0.x, v0.y, v0.z, v0.w, v1.x, v1.y, v1.z, v1.w};
  #pragma unroll
  for (int q = 0; q < 8; ++q) {
    _Float16 h = (_Float16)e[q];
    hv[q] = h;
    lv[q] = (_Float16)(e[q] - (float)h);
  }
  if (!isB) {
    *(half8*)(Ahi + (size_t)desc * D_ + seg * 8) = hv;
    *(half8*)(Alo + (size_t)desc * D_ + seg * 8) = lv;
  } else {
    int t   = desc >> 7, cloc = desc & 127;
    int nf  = cloc >> 4, c15  = cloc & 15;
    int kk  = seg >> 2,  gq   = seg & 3;
    size_t off = (size_t)t * 16384 + kk * 4096 + nf * 512 + gq * 128 + c15 * 8;
    *(half8*)(BhiP + off) = hv;
    *(half8*)(BloP + off) = lv;
  }
}

// LDS (dynamic 64KB): [0,32K) B_hi tile (fragment-linear), [32K,64K) B_lo tile.
__global__ __launch_bounds__(256, 2)
void nn_mfma(const _Float16* __restrict__ Ahi, const _Float16* __restrict__ Alo,
             const _Float16* __restrict__ BhiP, const _Float16* __restrict__ BloP,
             const float* __restrict__ sqb,
             float* __restrict__ p_d0, float* __restrict__ p_d1,
             int* __restrict__ p_j0, int B) {
  extern __shared__ char smem[];
  const int tid  = threadIdx.x;
  const int lane = tid & 63;
  const int wid  = tid >> 6;
  const int wr   = wid >> 1;       // row half (0,1): rows wr*32..wr*32+31
  const int wc   = wid & 1;        // col half (0,1): cols wc*64..wc*64+63
  const int l15  = lane & 15;
  const int g    = lane >> 4;

  const int nrb   = B / BM_;            // 256
  const int rb    = blockIdx.x % nrb;
  const int cspl  = blockIdx.x / nrb;
  const int i0    = rb * BM_;
  const int niter = (B / CS_) / BN_;    // 64
  const int tile0 = cspl * niter;

  // ---- A fragments -> registers, once ----
  half8 ah[2][4], al[2][4];
  #pragma unroll
  for (int mf = 0; mf < 2; ++mf) {
    int row = i0 + wr * 32 + mf * 16 + l15;
    const _Float16* pa = Ahi + (size_t)row * D_ + g * 8;
    const _Float16* pl = Alo + (size_t)row * D_ + g * 8;
    #pragma unroll
    for (int kk = 0; kk < 4; ++kk) {
      ah[mf][kk] = *(const half8*)(pa + kk * 32);
      al[mf][kk] = *(const half8*)(pl + kk * 32);
    }
  }

  // ---- staging: wave stages 8 chunks (1KB each) per plane via global_load_lds ----
  const _Float16* srcH = BhiP + (size_t)tile0 * 16384 + wid * 4096 + lane * 8;
  const _Float16* srcL = BloP + (size_t)tile0 * 16384 + wid * 4096 + lane * 8;
  char* ldsH = smem + wid * 8192;
  char* ldsL = smem + 32768 + wid * 8192;

  const int rdbase = lane * 16 + wc * 4096;   // + kk*8192 + nf*1024 (+32768 for lo)
  const int colg0  = tile0 * BN_ + wc * 64 + l15;

  float best0[8], best1[8]; int bj[8];
  #pragma unroll
  for (int s = 0; s < 8; ++s) { best0[s] = FLT_MAX; best1[s] = FLT_MAX; bj[s] = 0x7fffffff; }

  for (int it = 0; it < niter; ++it) {
    __syncthreads();   // all waves done reading previous tile
    #pragma unroll
    for (int e = 0; e < 8; ++e) gload_lds16(srcH + e * 512, ldsH + e * 1024);
    #pragma unroll
    for (int e = 0; e < 8; ++e) gload_lds16(srcL + e * 512, ldsL + e * 1024);
    srcH += 16384;
    srcL += 16384;
    __syncthreads();   // vmcnt drained by barrier: tile visible

    f32x4 acc[2][4];
    #pragma unroll
    for (int mf = 0; mf < 2; ++mf)
      #pragma unroll
      for (int nf = 0; nf < 4; ++nf) acc[mf][nf] = (f32x4){0.f, 0.f, 0.f, 0.f};

    #pragma unroll
    for (int kk = 0; kk < 4; ++kk) {
      half8 bh[4], bl[4];
      #pragma unroll
      for (int nf = 0; nf < 4; ++nf) {
        bh[nf] = *(const half8*)(smem + rdbase + kk * 8192 + nf * 1024);
        bl[nf] = *(const half8*)(smem + rdbase + kk * 8192 + nf * 1024 + 32768);
      }
      #pragma unroll
      for (int mf = 0; mf < 2; ++mf)
        #pragma unroll
        for (int nf = 0; nf < 4; ++nf) {
          acc[mf][nf] = __builtin_amdgcn_mfma_f32_16x16x32_f16(ah[mf][kk], bh[nf], acc[mf][nf], 0, 0, 0);
          acc[mf][nf] = __builtin_amdgcn_mfma_f32_16x16x32_f16(ah[mf][kk], bl[nf], acc[mf][nf], 0, 0, 0);
          acc[mf][nf] = __builtin_amdgcn_mfma_f32_16x16x32_f16(al[mf][kk], bh[nf], acc[mf][nf], 0, 0, 0);
        }
    }

    // ---- branchless top-2 fold. C/D layout: col = lane&15, row = (lane>>4)*4 + reg ----
    #pragma unroll
    for (int nf = 0; nf < 4; ++nf) {
      int colg = colg0 + it * BN_ + nf * 16;
      float sj = sqb[colg];
      #pragma unroll
      for (int mf = 0; mf < 2; ++mf)
        #pragma unroll
        for (int r = 0; r < 4; ++r) {
          int s = mf * 4 + r;
          float t = fmaf(-2.f, acc[mf][nf][r], sj);
          bool lt0 = t < best0[s];
          best1[s] = fminf(best1[s], fmaxf(t, best0[s]));
          best0[s] = fminf(t, best0[s]);
          bj[s]    = lt0 ? colg : bj[s];
        }
    }
  }

  // ---- merge across the 16 col-lanes (same g), index tie-break ----
  #pragma unroll
  for (int off = 1; off < 16; off <<= 1) {
    #pragma unroll
    for (int s = 0; s < 8; ++s) {
      float e0 = __shfl_xor(best0[s], off, 64);
      float e1 = __shfl_xor(best1[s], off, 64);
      int   f0 = __shfl_xor(bj[s],    off, 64);
      if (e0 < best0[s] || (e0 == best0[s] && f0 < bj[s])) {
        best1[s] = fminf(best0[s], e1);
        best0[s] = e0;
        bj[s]    = f0;
      } else {
        best1[s] = fminf(best1[s], e0);
      }
    }
  }

  if (l15 == 0) {
    int part = cspl * 2 + wc;
    #pragma unroll
    for (int s = 0; s < 8; ++s) {
      int mf = s >> 2, r = s & 3;
      int row = i0 + wr * 32 + mf * 16 + g * 4 + r;
      p_d0[row * PARTS_ + part] = best0[s];
      p_d1[row * PARTS_ + part] = best1[s];
      p_j0[row * PARTS_ + part] = bj[s];
    }
  }
}

__global__ void nn_final(const float* __restrict__ sqa,
                         const float* __restrict__ p_d0,
                         const float* __restrict__ p_d1,
                         const int* __restrict__ p_j0,
                         float* __restrict__ out, int B) {
  int row = blockIdx.x * blockDim.x + threadIdx.x;
  if (row >= B) return;
  float d0 = FLT_MAX, d1 = FLT_MAX;
  int j0 = 0x7fffffff;
  for (int cs = 0; cs < PARTS_; ++cs) {
    float e0 = p_d0[row * PARTS_ + cs];
    float e1 = p_d1[row * PARTS_ + cs];
    int   f0 = p_j0[row * PARTS_ + cs];
    if (e0 < d0 || (e0 == d0 && f0 < j0)) {
      d1 = fminf(d0, e1);
      d0 = e0;
      j0 = f0;
    } else {
      d1 = fminf(d1, e0);
    }
  }
  float sa = sqa[row];
  float v0 = sqrtf(fmaxf(sa + d0, 0.f));
  float v1 = sqrtf(fmaxf(sa + d1, 0.f));
  float ratio = v0 / v1;
  bool m = (ratio <= 0.8f);
  out[row]             = m ? ratio : 0.f;
  out[B + row * 2]     = (float)row;
  out[B + row * 2 + 1] = (float)j0;
  out[3 * B + row]     = m ? 1.f : 0.f;
}

extern "C" void kernel_launch(void* const* d_in, const int* in_sizes, int n_in,
                              void* d_out, int out_size, void* d_ws, size_t ws_size,
                              hipStream_t stream) {
  const float* d1 = (const float*)d_in[0];
  const float* d2 = (const float*)d_in[1];
  const int B = in_sizes[0] / D_;    // 16384

  float* ws   = (float*)d_ws;
  float* sqa  = ws;                       // [0, B)
  float* sqb  = ws + B;                   // [B, 2B)
  float* p_d0 = ws + 2 * B;               // [2B, 6B)
  float* p_d1 = ws + 6 * B;               // [6B, 10B)
  int*   p_j0 = (int*)(ws + 10 * B);      // [10B, 14B)
  _Float16* Ahi  = (_Float16*)(ws + 14 * B);
  _Float16* Alo  = Ahi + (size_t)B * D_;
  _Float16* BhiP = Alo + (size_t)B * D_;
  _Float16* BloP = BhiP + (size_t)B * D_;

  // norms
  int nthreads = 2 * B * 64;
  norms_kernel<<<(nthreads + 255) / 256, 256, 0, stream>>>(d1, d2, sqa, B);

  // f32 -> f16 hi/lo planes (A row-major, B fragment-packed)
  int ngroups = 2 * B * 16;
  convert_kernel<<<(ngroups + 255) / 256, 256, 0, stream>>>(d1, d2, Ahi, Alo, BhiP, BloP, B);

  // main MFMA kernel: 64 KiB dynamic LDS, 2 blocks/CU
  hipFuncSetAttribute((const void*)nn_mfma,
                      hipFuncAttributeMaxDynamicSharedMemorySize, 65536);
  nn_mfma<<<(B / BM_) * CS_, 256, 65536, stream>>>(Ahi, Alo, BhiP, BloP, sqb,
                                                   p_d0, p_d1, p_j0, B);

  // final merge + outputs
  nn_final<<<(B + 255) / 256, 256, 0, stream>>>(sqa, p_d0, p_d1, p_j0, (float*)d_out, B);
}

// Round 6
// 194.502 us; speedup vs baseline: 6.3647x; 1.0741x over previous
//
#include <hip/hip_runtime.h>
#include <math.h>
#include <float.h>
#include <stdint.h>

// NearestNeighborRatio: desc1/desc2 (B=16384, D=128) f32.
// d2(i,j) = |a_i|^2 + |b_j|^2 - 2 a_i.b_j; per-row top-2, ratio = sqrt(d0/d1), mask = ratio<=0.8.
// f16 hi/lo split (x = hi + lo): dot via 3 MFMAs (hh + hl + lh) in fp32 acc.
// v5: 2-phase double-buffered B staging (BN=64, 2x32KB LDS); B planes pre-scaled by -2;
//     sqb folded into the MFMA C operand -> acc = sqb[j] - 2*dot directly.
// Out (flat f32): [0,B) match_dists ; [B,3B) matches_idxs as floats ; [3B,4B) mask 0/1.

typedef __attribute__((ext_vector_type(4))) float     f32x4;
typedef __attribute__((ext_vector_type(8))) _Float16  half8;

#define D_     128
#define BM_    128   // rows per block (4 waves x 32)
#define BN_    64    // cols per iter (= one packed tile)
#define CS_    4     // column splits
#define PARTS_ 4     // partials per row = CS_

__device__ __forceinline__ void gload_lds16(const void* g, void* l) {
  auto gp = (const __attribute__((address_space(1))) unsigned int*)(uintptr_t)g;
  auto lp = (__attribute__((address_space(3))) unsigned int*)(uintptr_t)l;
  __builtin_amdgcn_global_load_lds(gp, lp, 16, 0, 0);
}

__global__ void norms_kernel(const float* __restrict__ d1,
                             const float* __restrict__ d2,
                             float* __restrict__ sq, int B) {
  int gid  = blockIdx.x * blockDim.x + threadIdx.x;
  int wid  = gid >> 6;
  int lane = gid & 63;
  if (wid >= 2 * B) return;
  const float* src = (wid < B) ? (d1 + (size_t)wid * D_)
                               : (d2 + (size_t)(wid - B) * D_);
  float2 v = ((const float2*)src)[lane];
  float s = fmaf(v.x, v.x, v.y * v.y);
  #pragma unroll
  for (int off = 32; off > 0; off >>= 1) s += __shfl_down(s, off, 64);
  if (lane == 0) sq[wid] = s;
}

// A planes: row-major [B][128] f16 (unscaled).
// B planes: packed fragment order per 64-col tile, PRE-SCALED BY -2:
//   f16 offset = t*8192 + kk*2048 + nf*512 + g*128 + c15*8
//   holds -2*desc2[t*64 + nf*16 + c15][kk*32 + g*8 .. +8]
__global__ void convert_kernel(const float* __restrict__ d1, const float* __restrict__ d2,
                               _Float16* __restrict__ Ahi, _Float16* __restrict__ Alo,
                               _Float16* __restrict__ BhiP, _Float16* __restrict__ BloP,
                               int B) {
  int i = blockIdx.x * blockDim.x + threadIdx.x;
  int total = B * 16;                       // 8-elem groups per matrix
  if (i >= 2 * total) return;
  bool isB = i >= total;
  int j    = isB ? i - total : i;
  int desc = j >> 4;
  int seg  = j & 15;                        // 8-f32 group within the row
  const float* src = (isB ? d2 : d1) + (size_t)desc * D_ + seg * 8;
  float4 v0 = *(const float4*)(src);
  float4 v1 = *(const float4*)(src + 4);
  half8 hv, lv;
  float e[8] = {v0.x, v0.y, v0.z, v0.w, v1.x, v1.y, v1.z, v1.w};
  #pragma unroll
  for (int q = 0; q < 8; ++q) {
    _Float16 h = (_Float16)e[q];
    _Float16 l = (_Float16)(e[q] - (float)h);
    if (isB) { h = (_Float16)(-2.0f) * h; l = (_Float16)(-2.0f) * l; }
    hv[q] = h; lv[q] = l;
  }
  if (!isB) {
    *(half8*)(Ahi + (size_t)desc * D_ + seg * 8) = hv;
    *(half8*)(Alo + (size_t)desc * D_ + seg * 8) = lv;
  } else {
    int t   = desc >> 6, cloc = desc & 63;
    int nf  = cloc >> 4, c15  = cloc & 15;
    int kk  = seg >> 2,  gq   = seg & 3;
    size_t off = (size_t)t * 8192 + kk * 2048 + nf * 512 + gq * 128 + c15 * 8;
    *(half8*)(BhiP + off) = hv;
    *(half8*)(BloP + off) = lv;
  }
}

// LDS (dynamic 64KB): buf0 [0,32K), buf1 [32K,64K).
// Within a buf: [0,16K) hi plane, [16K,32K) lo plane; chunk (kk,nf) at kk*4096+nf*1024,
// lane's half8 at +lane*16 (fragment-linear -> zero bank conflicts).
__global__ __launch_bounds__(256, 2)
void nn_mfma(const _Float16* __restrict__ Ahi, const _Float16* __restrict__ Alo,
             const _Float16* __restrict__ BhiP, const _Float16* __restrict__ BloP,
             const float* __restrict__ sqb,
             float* __restrict__ p_d0, float* __restrict__ p_d1,
             int* __restrict__ p_j0, int B) {
  extern __shared__ char smem[];
  const int tid  = threadIdx.x;
  const int lane = tid & 63;
  const int wid  = tid >> 6;       // wave row-group: rows wid*32..wid*32+31
  const int l15  = lane & 15;
  const int g    = lane >> 4;

  const int nrb   = B / BM_;            // 128
  const int rb    = blockIdx.x % nrb;
  const int cspl  = blockIdx.x / nrb;
  const int i0    = rb * BM_;
  const int niter = (B / CS_) / BN_;    // 64
  const int tile0 = cspl * niter;

  // ---- A fragments -> registers, once ----
  half8 ah[2][4], al[2][4];
  #pragma unroll
  for (int mf = 0; mf < 2; ++mf) {
    int row = i0 + wid * 32 + mf * 16 + l15;
    const _Float16* pa = Ahi + (size_t)row * D_ + g * 8;
    const _Float16* pl = Alo + (size_t)row * D_ + g * 8;
    #pragma unroll
    for (int kk = 0; kk < 4; ++kk) {
      ah[mf][kk] = *(const half8*)(pa + kk * 32);
      al[mf][kk] = *(const half8*)(pl + kk * 32);
    }
  }

  // ---- staging helper: wave wid stages chunks [wid*4, wid*4+4) per plane ----
  const _Float16* srcH0 = BhiP + (size_t)tile0 * 8192 + wid * 2048 + lane * 8;
  const _Float16* srcL0 = BloP + (size_t)tile0 * 8192 + wid * 2048 + lane * 8;
  char* ldsHW = smem + wid * 4096;          // + bufbase; lo plane +16384
  auto stage = [&](int bufbase, int it) {
    const _Float16* sH = srcH0 + (size_t)it * 8192;
    const _Float16* sL = srcL0 + (size_t)it * 8192;
    char* lH = ldsHW + bufbase;
    char* lL = ldsHW + bufbase + 16384;
    #pragma unroll
    for (int e = 0; e < 4; ++e) gload_lds16(sH + e * 512, lH + e * 1024);
    #pragma unroll
    for (int e = 0; e < 4; ++e) gload_lds16(sL + e * 512, lL + e * 1024);
  };

  float best0[8], best1[8]; int bj[8];
  #pragma unroll
  for (int s = 0; s < 8; ++s) { best0[s] = FLT_MAX; best1[s] = FLT_MAX; bj[s] = 0x7fffffff; }

  float sjA[4], sjB[4];
  const int colg0 = tile0 * BN_ + l15;

  // ---- prologue: stage tile 0 into buf0; prefetch sj for it=0 ----
  stage(0, 0);
  #pragma unroll
  for (int nf = 0; nf < 4; ++nf) sjA[nf] = sqb[colg0 + nf * 16];
  __syncthreads();

  auto body = [&](int it, int bufbase, float (&sjc)[4], float (&sjn)[4]) {
    // stage next tile into the other buffer (safe: barrier at end of prev iter)
    if (it + 1 < niter) {
      stage(bufbase ^ 32768, it + 1);
      #pragma unroll
      for (int nf = 0; nf < 4; ++nf) sjn[nf] = sqb[colg0 + (it + 1) * BN_ + nf * 16];
    }

    f32x4 acc[2][4];
    #pragma unroll
    for (int kk = 0; kk < 4; ++kk) {
      half8 bh[4], bl[4];
      #pragma unroll
      for (int nf = 0; nf < 4; ++nf) {
        bh[nf] = *(const half8*)(smem + bufbase + kk * 4096 + nf * 1024 + lane * 16);
        bl[nf] = *(const half8*)(smem + bufbase + 16384 + kk * 4096 + nf * 1024 + lane * 16);
      }
      #pragma unroll
      for (int mf = 0; mf < 2; ++mf)
        #pragma unroll
        for (int nf = 0; nf < 4; ++nf) {
          if (kk == 0) {
            f32x4 c0 = {sjc[nf], sjc[nf], sjc[nf], sjc[nf]};
            acc[mf][nf] = __builtin_amdgcn_mfma_f32_16x16x32_f16(ah[mf][0], bh[nf], c0, 0, 0, 0);
          } else {
            acc[mf][nf] = __builtin_amdgcn_mfma_f32_16x16x32_f16(ah[mf][kk], bh[nf], acc[mf][nf], 0, 0, 0);
          }
          acc[mf][nf] = __builtin_amdgcn_mfma_f32_16x16x32_f16(ah[mf][kk], bl[nf], acc[mf][nf], 0, 0, 0);
          acc[mf][nf] = __builtin_amdgcn_mfma_f32_16x16x32_f16(al[mf][kk], bh[nf], acc[mf][nf], 0, 0, 0);
        }
    }

    // ---- branchless top-2 fold; acc[r] = sqb[j] - 2*dot already ----
    // C/D layout: col = lane&15, row = (lane>>4)*4 + reg
    #pragma unroll
    for (int nf = 0; nf < 4; ++nf) {
      int colg = colg0 + it * BN_ + nf * 16;
      #pragma unroll
      for (int mf = 0; mf < 2; ++mf)
        #pragma unroll
        for (int r = 0; r < 4; ++r) {
          int s = mf * 4 + r;
          float t = acc[mf][nf][r];
          bool lt0 = t < best0[s];
          best1[s] = fminf(best1[s], fmaxf(t, best0[s]));
          best0[s] = fminf(t, best0[s]);
          bj[s]    = lt0 ? colg : bj[s];
        }
    }
    __syncthreads();   // next buffer staged & visible; this buffer free for overwrite
  };

  for (int itp = 0; itp < niter; itp += 2) {
    body(itp,     0,     sjA, sjB);
    body(itp + 1, 32768, sjB, sjA);
  }

  // ---- merge across the 16 col-lanes (same g), index tie-break ----
  #pragma unroll
  for (int off = 1; off < 16; off <<= 1) {
    #pragma unroll
    for (int s = 0; s < 8; ++s) {
      float e0 = __shfl_xor(best0[s], off, 64);
      float e1 = __shfl_xor(best1[s], off, 64);
      int   f0 = __shfl_xor(bj[s],    off, 64);
      if (e0 < best0[s] || (e0 == best0[s] && f0 < bj[s])) {
        best1[s] = fminf(best0[s], e1);
        best0[s] = e0;
        bj[s]    = f0;
      } else {
        best1[s] = fminf(best1[s], e0);
      }
    }
  }

  if (l15 == 0) {
    #pragma unroll
    for (int s = 0; s < 8; ++s) {
      int mf = s >> 2, r = s & 3;
      int row = i0 + wid * 32 + mf * 16 + g * 4 + r;
      p_d0[row * PARTS_ + cspl] = best0[s];
      p_d1[row * PARTS_ + cspl] = best1[s];
      p_j0[row * PARTS_ + cspl] = bj[s];
    }
  }
}

__global__ void nn_final(const float* __restrict__ sqa,
                         const float* __restrict__ p_d0,
                         const float* __restrict__ p_d1,
                         const int* __restrict__ p_j0,
                         float* __restrict__ out, int B) {
  int row = blockIdx.x * blockDim.x + threadIdx.x;
  if (row >= B) return;
  float d0 = FLT_MAX, d1 = FLT_MAX;
  int j0 = 0x7fffffff;
  for (int cs = 0; cs < PARTS_; ++cs) {
    float e0 = p_d0[row * PARTS_ + cs];
    float e1 = p_d1[row * PARTS_ + cs];
    int   f0 = p_j0[row * PARTS_ + cs];
    if (e0 < d0 || (e0 == d0 && f0 < j0)) {
      d1 = fminf(d0, e1);
      d0 = e0;
      j0 = f0;
    } else {
      d1 = fminf(d1, e0);
    }
  }
  float sa = sqa[row];
  float v0 = sqrtf(fmaxf(sa + d0, 0.f));
  float v1 = sqrtf(fmaxf(sa + d1, 0.f));
  float ratio = v0 / v1;
  bool m = (ratio <= 0.8f);
  out[row]             = m ? ratio : 0.f;
  out[B + row * 2]     = (float)row;
  out[B + row * 2 + 1] = (float)j0;
  out[3 * B + row]     = m ? 1.f : 0.f;
}

extern "C" void kernel_launch(void* const* d_in, const int* in_sizes, int n_in,
                              void* d_out, int out_size, void* d_ws, size_t ws_size,
                              hipStream_t stream) {
  const float* d1 = (const float*)d_in[0];
  const float* d2 = (const float*)d_in[1];
  const int B = in_sizes[0] / D_;    // 16384

  float* ws   = (float*)d_ws;
  float* sqa  = ws;                       // [0, B)
  float* sqb  = ws + B;                   // [B, 2B)
  float* p_d0 = ws + 2 * B;               // [2B, 6B)
  float* p_d1 = ws + 6 * B;               // [6B, 10B)
  int*   p_j0 = (int*)(ws + 10 * B);      // [10B, 14B)
  _Float16* Ahi  = (_Float16*)(ws + 14 * B);
  _Float16* Alo  = Ahi + (size_t)B * D_;
  _Float16* BhiP = Alo + (size_t)B * D_;
  _Float16* BloP = BhiP + (size_t)B * D_;

  // norms
  int nthreads = 2 * B * 64;
  norms_kernel<<<(nthreads + 255) / 256, 256, 0, stream>>>(d1, d2, sqa, B);

  // f32 -> f16 hi/lo planes (A row-major; B fragment-packed, scaled by -2)
  int ngroups = 2 * B * 16;
  convert_kernel<<<(ngroups + 255) / 256, 256, 0, stream>>>(d1, d2, Ahi, Alo, BhiP, BloP, B);

  // main MFMA kernel: 64 KiB dynamic LDS, 2 blocks/CU
  hipFuncSetAttribute((const void*)nn_mfma,
                      hipFuncAttributeMaxDynamicSharedMemorySize, 65536);
  nn_mfma<<<(B / BM_) * CS_, 256, 65536, stream>>>(Ahi, Alo, BhiP, BloP, sqb,
                                                   p_d0, p_d1, p_j0, B);

  // final merge + outputs
  nn_final<<<(B + 255) / 256, 256, 0, stream>>>(sqa, p_d0, p_d1, p_j0, (float*)d_out, B);
}